// Round 17
// baseline (243.784 us; speedup 1.0000x reference)
//
#include <hip/hip_runtime.h>
#include <hip/hip_bf16.h>
#include <math.h>

#define DIM 128
#define TOPK 128
#define CAP 4096
#define HSIZE 16384
#define HSHIFT 18          // f2k >> 18 -> 14-bit bin
#define HMUL 10937u        // odd -> bijective mod 2^14
#define BSTRIDE 64         // fixed slots per destination bucket (Poisson(16) tail << 64)

typedef __attribute__((ext_vector_type(8))) short bf16x8;
typedef __attribute__((ext_vector_type(4))) float f32x4;

__device__ __forceinline__ unsigned f2k(float f) {
    unsigned b = __float_as_uint(f);
    return (b & 0x80000000u) ? ~b : (b | 0x80000000u);
}

__device__ __forceinline__ unsigned hidx(unsigned bin) {
    return (bin * HMUL) & (HSIZE - 1u);
}

// round-to-nearest-even bf16 (as high 16 bits of fp32)
__device__ __forceinline__ unsigned bf16rn(float v) {
    unsigned u = __float_as_uint(v);
    u += 0x7fffu + ((u >> 16) & 1u);
    return u >> 16;
}

__device__ __forceinline__ unsigned pack2bf(float lo, float hi) {
    return (bf16rn(hi) << 16) | bf16rn(lo);
}

// one u64 atomic per edge: [63:40] count, [39:0] fixed-point weight sum (2^-32).
// seq from returned old value -> direct store into fixed-stride bucket.
__device__ __forceinline__ void deg_edge(const int* __restrict__ ei, const float* __restrict__ ew,
                                         unsigned long long* __restrict__ packed,
                                         int2* __restrict__ edata2, int ne, int e) {
    int c = ei[ne + e];
    float w = ew[e];
    unsigned long long fx = (unsigned long long)((double)w * 4294967296.0);
    unsigned long long old = atomicAdd(&packed[c], (1ull << 40) | fx);
    int seq = (int)(old >> 40);
    if (seq < BSTRIDE)
        edata2[((size_t)c << 6) + seq] = make_int2(ei[e], __float_as_int(w));
}

// Bresenham interleave of degB deg-blocks among T total blocks.
__device__ __forceinline__ bool pick_deg(int bid, int degB, int T, int* mi, int* di) {
    long long a = (long long)bid * degB;
    int before = (int)(a / T);
    if ((int)((a + degB) / T) > before) { *di = before; return true; }
    *mi = bid - before;
    return false;
}

// 16 lanes per node (2x float4 each): UNSCALED score + spread-hist bin, + deg slice
__global__ void k_score_deg(const float* __restrict__ x, const float* __restrict__ p,
                            float* __restrict__ score,
                            unsigned* __restrict__ hist, int n,
                            int degB, const int* __restrict__ ei, const float* __restrict__ ew,
                            unsigned long long* __restrict__ packed,
                            int2* __restrict__ edata2,
                            int e0, int e1, int ne) {
    int mi, di;
    if (pick_deg((int)blockIdx.x, degB, (int)gridDim.x, &mi, &di)) {
        int e = e0 + di * 256 + (int)threadIdx.x;
        if (e < e1) deg_edge(ei, ew, packed, edata2, ne, e);
        return;
    }
    int gid = mi * 256 + (int)threadIdx.x;
    int node = gid >> 4, lane = gid & 15;
    if (node >= n) return;
    const float4* xr = (const float4*)(x) + (size_t)node * 32;
    const float4* p4 = (const float4*)p;
    float4 a0 = xr[lane * 2], a1 = xr[lane * 2 + 1];
    float4 b0 = p4[lane * 2], b1 = p4[lane * 2 + 1];
    float acc = a0.x * b0.x + a0.y * b0.y + a0.z * b0.z + a0.w * b0.w +
                a1.x * b1.x + a1.y * b1.y + a1.z * b1.z + a1.w * b1.w;
#pragma unroll
    for (int m = 8; m >= 1; m >>= 1) acc += __shfl_xor(acc, m, 16);
    if (lane == 0) {
        score[node] = acc;                     // raw dot; ordering is scale-invariant
        atomicAdd(&hist[hidx(f2k(acc) >> HSHIFT)], 1u);
    }
}

// block 0: find threshold bin (16 bins/thread) + compute pinv; other blocks: deg slice
__global__ void k_findbin_deg(const unsigned* __restrict__ hist, unsigned* __restrict__ binfo,
                              int k, const float* __restrict__ p, float* __restrict__ pinv,
                              const int* __restrict__ ei, const float* __restrict__ ew,
                              unsigned long long* __restrict__ packed,
                              int2* __restrict__ edata2,
                              int e0, int e1, int ne) {
    if (blockIdx.x > 0) {
        int e = e0 + ((int)blockIdx.x - 1) * 1024 + (int)threadIdx.x;
        if (e < e1) deg_edge(ei, ew, packed, edata2, ne, e);
        return;
    }
    __shared__ unsigned csum[1024];
    __shared__ float ps[DIM];
    int t = threadIdx.x;
    if (t < DIM) { float v = p[t]; ps[t] = v * v; }
    unsigned hv[16];
    unsigned s = 0;
#pragma unroll
    for (int j = 0; j < 16; ++j) {
        hv[j] = hist[hidx(t * 16 + j)];
        s += hv[j];
    }
    csum[t] = s;
    __syncthreads();
    if (t < 64) {
        for (int off = 64; off > 0; off >>= 1) {
            if (t < off) ps[t] += ps[t + off];
        }
    }
    if (t == 0) pinv[0] = 1.0f / sqrtf(ps[0] + ps[1]);   // tree leaves ps[0],ps[1] summed
    for (int off = 1; off < 1024; off <<= 1) {
        unsigned v = (t + off < 1024) ? csum[t + off] : 0u;
        __syncthreads();
        csum[t] += v;
        __syncthreads();
    }
    unsigned run = (t + 1 < 1024) ? csum[t + 1] : 0u;
#pragma unroll
    for (int j = 15; j >= 0; --j) {
        unsigned h = hv[j];
        if (h > 0u && run < (unsigned)k && run + h >= (unsigned)k) {
            binfo[0] = (unsigned)(t * 16 + j);
            binfo[1] = run;
        }
        run += h;
    }
}

__global__ void k_collect_deg(const float* __restrict__ score, const unsigned* __restrict__ binfo,
                              unsigned* __restrict__ counter, float* __restrict__ cval,
                              int* __restrict__ cidx, int n,
                              int degB, const int* __restrict__ ei, const float* __restrict__ ew,
                              unsigned long long* __restrict__ packed,
                              int2* __restrict__ edata2,
                              int e0, int e1, int ne) {
    int mi, di;
    if (pick_deg((int)blockIdx.x, degB, (int)gridDim.x, &mi, &di)) {
        int e = e0 + di * 256 + (int)threadIdx.x;
        if (e < e1) deg_edge(ei, ew, packed, edata2, ne, e);
        return;
    }
    int i = mi * 256 + (int)threadIdx.x;
    if (i >= n) return;
    float s = score[i];
    if ((f2k(s) >> HSHIFT) >= binfo[0]) {
        unsigned pos = atomicAdd(counter, 1u);
        if (pos < CAP) { cval[pos] = s; cidx[pos] = i; }
    }
}

// rank-based exact top-k (matches jax.lax.top_k: desc, lower index wins ties)
__global__ void k_rank_deg(const float* __restrict__ cval, const int* __restrict__ cidx,
                           const unsigned* __restrict__ counter, int* __restrict__ perm,
                           float* __restrict__ vals, int k,
                           int degB, const int* __restrict__ ei, const float* __restrict__ ew,
                           unsigned long long* __restrict__ packed,
                           int2* __restrict__ edata2,
                           int e0, int e1, int ne) {
    int mi, di;
    if (pick_deg((int)blockIdx.x, degB, (int)gridDim.x, &mi, &di)) {
        int e = e0 + di * 256 + (int)threadIdx.x;
        if (e < e1) deg_edge(ei, ew, packed, edata2, ne, e);
        return;
    }
    int i = mi * 256 + (int)threadIdx.x;
    unsigned cnt = counter[0];
    int m = (cnt < (unsigned)CAP) ? (int)cnt : CAP;
    if (i >= m) return;
    float v = cval[i]; int id = cidx[i];
    int rank = 0;
    for (int j = 0; j < m; ++j) {
        float vj = cval[j]; int ij = cidx[j];
        if (vj > v || (vj == v && ij < id)) ++rank;
    }
    if (rank < k) { perm[rank] = id; vals[rank] = v; }
}

// GRU with fused x_tilde (vals scaled by pinv here) + deg slice; writes W^T bf16
__global__ void k_gru_deg(const float* __restrict__ x, const int* __restrict__ perm,
                          const float* __restrict__ vals, const float* __restrict__ pinv,
                          const float* __restrict__ W0,
                          const float* __restrict__ w_ih, const float* __restrict__ w_hh,
                          const float* __restrict__ b_ih, const float* __restrict__ b_hh,
                          unsigned short* __restrict__ WhT,
                          int degB, const int* __restrict__ ei, const float* __restrict__ ew,
                          unsigned long long* __restrict__ packed,
                          int2* __restrict__ edata2,
                          int e0, int e1, int ne) {
    __shared__ float sx[DIM], sh[DIM];
    int mi, di;
    if (pick_deg((int)blockIdx.x, degB, (int)gridDim.x, &mi, &di)) {
        int e = e0 + di * 128 + (int)threadIdx.x;
        if (e < e1) deg_edge(ei, ew, packed, edata2, ne, e);
        return;
    }
    int i = mi, c = threadIdx.x;
    sx[c] = x[(size_t)perm[i] * DIM + c] * tanhf(vals[i] * pinv[0]);
    sh[c] = W0[i * DIM + c];
    __syncthreads();
    float gr = b_ih[c], gz = b_ih[DIM + c], gn = b_ih[2 * DIM + c];
    float hr = b_hh[c], hz = b_hh[DIM + c], hn = b_hh[2 * DIM + c];
    const float* wr = w_ih + (size_t)c * DIM;
    const float* wz = w_ih + (size_t)(DIM + c) * DIM;
    const float* wn = w_ih + (size_t)(2 * DIM + c) * DIM;
    const float* ur = w_hh + (size_t)c * DIM;
    const float* uz = w_hh + (size_t)(DIM + c) * DIM;
    const float* un = w_hh + (size_t)(2 * DIM + c) * DIM;
    for (int d = 0; d < DIM; ++d) {
        float xd = sx[d], hd = sh[d];
        gr += xd * wr[d]; gz += xd * wz[d]; gn += xd * wn[d];
        hr += hd * ur[d]; hz += hd * uz[d]; hn += hd * un[d];
    }
    float r = 1.0f / (1.0f + expf(-(gr + hr)));
    float z = 1.0f / (1.0f + expf(-(gz + hz)));
    float nn = tanhf(gn + r * hn);
    float wv = (1.0f - z) * nn + z * sh[c];
    WhT[(size_t)c * DIM + i] = (unsigned short)bf16rn(wv);   // transposed bf16
}

// xw = x @ W -> bf16 via MFMA 16x16x32. 64x64 tile, 4 waves, 16KB LDS (bf16 x-tile,
// granule-XOR swizzle). W^T bf16 read from global (32KB, L2-resident).
__global__ __launch_bounds__(256) void k_xw_deg(const float* __restrict__ x,
                                                const unsigned short* __restrict__ WhT,
                                                unsigned short* __restrict__ xwh, int n,
                                                int degB, const int* __restrict__ ei,
                                                const float* __restrict__ ew,
                                                unsigned long long* __restrict__ packed,
                                                int2* __restrict__ edata2,
                                                int e0, int e1, int ne) {
    __shared__ unsigned short xs[64 * DIM];   // 16KB: [r][k] bf16, granule g^=(r&7)
    int mi, di;
    if (pick_deg((int)blockIdx.x, degB, (int)gridDim.x, &mi, &di)) {
        int e = e0 + di * 256 + (int)threadIdx.x;
        if (e < e1) deg_edge(ei, ew, packed, edata2, ne, e);
        return;
    }
    int nTr = (n + 63) / 64;
    int r0 = (mi % nTr) * 64;
    int c0 = (mi / nTr) * 64;
    int t = threadIdx.x;
    {
        int r = t >> 2;
        int row = r0 + r; if (row >= n) row = n - 1;
        const float4* xr = (const float4*)(x + (size_t)row * DIM);
#pragma unroll
        for (int j = 0; j < 4; ++j) {
            int g = (t & 3) + 4 * j;
            float4 lo = xr[g * 2];
            float4 hi = xr[g * 2 + 1];
            uint4 o;
            o.x = pack2bf(lo.x, lo.y);
            o.y = pack2bf(lo.z, lo.w);
            o.z = pack2bf(hi.x, hi.y);
            o.w = pack2bf(hi.z, hi.w);
            *(uint4*)&xs[r * DIM + ((g ^ (r & 7)) << 3)] = o;
        }
    }
    __syncthreads();
    int wid = t >> 6, lane = t & 63;
    int lr = wid * 16 + (lane & 15);
    int kg = lane >> 4;
    int cA = lane & 15;
    f32x4 acc[4] = {{0.f,0.f,0.f,0.f},{0.f,0.f,0.f,0.f},{0.f,0.f,0.f,0.f},{0.f,0.f,0.f,0.f}};
    const bf16x8* wt = (const bf16x8*)WhT;
#pragma unroll
    for (int q = 0; q < 4; ++q) {
        bf16x8 a = *(const bf16x8*)&xs[lr * DIM + (((q * 4 + kg) ^ (lr & 7)) << 3)];
#pragma unroll
        for (int ct = 0; ct < 4; ++ct) {
            bf16x8 b = wt[(size_t)(c0 + ct * 16 + cA) * 16 + q * 4 + kg];
            acc[ct] = __builtin_amdgcn_mfma_f32_16x16x32_bf16(a, b, acc[ct], 0, 0, 0);
        }
    }
    int orow = r0 + wid * 16 + (lane >> 4) * 4;
#pragma unroll
    for (int reg = 0; reg < 4; ++reg) {
        int row = orow + reg;
        if (row < n) {
            unsigned short* dst = xwh + (size_t)row * DIM + c0 + cA;
#pragma unroll
            for (int ct = 0; ct < 4; ++ct)
                dst[ct * 16] = (unsigned short)bf16rn(acc[ct][reg]);
        }
    }
}

// unpack packed -> dinv + cnt (no scan needed with fixed-stride buckets)
__global__ void k_dinv(const unsigned long long* __restrict__ packed,
                       float* __restrict__ dinv, int* __restrict__ cnt, int n) {
    int i = blockIdx.x * blockDim.x + threadIdx.x;
    if (i < n) {
        unsigned long long pk = packed[i];
        float sumw = (float)((double)(pk & ((1ull << 40) - 1ull)) * (1.0 / 4294967296.0));
        dinv[i] = rsqrtf(1.0f + sumw);
        cnt[i] = (int)(pk >> 40);
    }
}

// per-node gather + fused relu-linear head: 16 lanes per node, 8 bf16 (16B) each.
// reads fixed-stride buckets; nrm computed inline (dinv is L2-resident).
__global__ __launch_bounds__(256) void k_gather(const unsigned short* __restrict__ xwh,
        const float* __restrict__ dinv, const int* __restrict__ cnt,
        const int2* __restrict__ edata2, const float* __restrict__ w_lin,
        const float* __restrict__ b_lin, float* __restrict__ out, int n) {
    int gid = blockIdx.x * 256 + threadIdx.x;
    int c = gid >> 4, lane = gid & 15;
    if (c >= n) return;
    const uint4* xw4 = (const uint4*)xwh;
    float dc = dinv[c];
    float dd = dc * dc;
    float acc[8];
    {
        uint4 a = xw4[(size_t)c * 16 + lane];
        unsigned w[4] = {a.x, a.y, a.z, a.w};
#pragma unroll
        for (int q = 0; q < 4; ++q) {
            acc[2 * q]     = __uint_as_float(w[q] << 16) * dd;
            acc[2 * q + 1] = __uint_as_float(w[q] & 0xffff0000u) * dd;
        }
    }
    int m0 = cnt[c]; if (m0 > BSTRIDE) m0 = BSTRIDE;
    const int2* bkt = edata2 + ((size_t)c << 6);
    for (int base = 0; base < m0; base += 16) {
        int m = m0 - base; if (m > 16) m = 16;
        int2 ed = (base + lane < m0) ? bkt[base + lane] : make_int2(0, 0);
        for (int j0 = 0; j0 < m; j0 += 8) {
            uint4 v[8]; float nr[8];
#pragma unroll
            for (int jj = 0; jj < 8; ++jj) {
                int j = j0 + jj;
                int src = __shfl(ed.x, j & 15, 16);
                float w = __int_as_float(__shfl(ed.y, j & 15, 16));
                nr[jj] = (j < m) ? dinv[src] * w * dc : 0.0f;
                v[jj] = xw4[(size_t)src * 16 + lane];
            }
#pragma unroll
            for (int jj = 0; jj < 8; ++jj) {
                unsigned w[4] = {v[jj].x, v[jj].y, v[jj].z, v[jj].w};
#pragma unroll
                for (int q = 0; q < 4; ++q) {
                    acc[2 * q]     += __uint_as_float(w[q] << 16) * nr[jj];
                    acc[2 * q + 1] += __uint_as_float(w[q] & 0xffff0000u) * nr[jj];
                }
            }
        }
    }
    float4 wla = ((const float4*)w_lin)[lane * 2];
    float4 wlb = ((const float4*)w_lin)[lane * 2 + 1];
    float r = fmaxf(acc[0], 0.0f) * wla.x + fmaxf(acc[1], 0.0f) * wla.y +
              fmaxf(acc[2], 0.0f) * wla.z + fmaxf(acc[3], 0.0f) * wla.w +
              fmaxf(acc[4], 0.0f) * wlb.x + fmaxf(acc[5], 0.0f) * wlb.y +
              fmaxf(acc[6], 0.0f) * wlb.z + fmaxf(acc[7], 0.0f) * wlb.w;
#pragma unroll
    for (int m = 8; m >= 1; m >>= 1) r += __shfl_xor(r, m, 16);
    if (lane == 0) out[c] = r + b_lin[0];
}

extern "C" void kernel_launch(void* const* d_in, const int* in_sizes, int n_in,
                              void* d_out, int out_size, void* d_ws, size_t ws_size,
                              hipStream_t stream) {
    const float* x     = (const float*)d_in[0];
    const int*   ei    = (const int*)d_in[1];
    const float* ew    = (const float*)d_in[2];
    const float* p     = (const float*)d_in[3];
    const float* W0    = (const float*)d_in[4];
    const float* w_ih  = (const float*)d_in[5];
    const float* w_hh  = (const float*)d_in[6];
    const float* b_ih  = (const float*)d_in[7];
    const float* b_hh  = (const float*)d_in[8];
    const float* w_lin = (const float*)d_in[9];
    const float* b_lin = (const float*)d_in[10];
    float* out = (float*)d_out;
    int n  = in_sizes[0] / DIM;
    int ne = in_sizes[2];
    (void)n_in; (void)out_size; (void)ws_size;

    char* base = (char*)d_ws;
    size_t o = 0;
    auto alloc = [&](size_t b) { size_t r = o; o += (b + 255) & ~(size_t)255; return r; };
    // packed+hist+counter contiguous -> single async memset zeroes all three
    size_t zero_beg = o;
    unsigned long long* packed = (unsigned long long*)(base + alloc((size_t)n * 8));
    unsigned* hist    = (unsigned*)(base + alloc(HSIZE * 4));
    unsigned* counter = (unsigned*)(base + alloc(256));
    size_t zero_len = o - zero_beg;
    float*    score   = (float*)(base + alloc((size_t)n * 4));
    unsigned* binfo   = (unsigned*)(base + alloc(256));
    float*    cval    = (float*)(base + alloc((size_t)CAP * 4));
    int*      cidx    = (int*)(base + alloc((size_t)CAP * 4));
    int*      perm    = (int*)(base + alloc(TOPK * 4));
    float*    vals    = (float*)(base + alloc(TOPK * 4));
    float*    pinv    = (float*)(base + alloc(256));
    unsigned short* WhT = (unsigned short*)(base + alloc(DIM * DIM * 2));
    float*    dinv    = (float*)(base + alloc((size_t)n * 4));
    int*      cnt     = (int*)(base + alloc((size_t)n * 4));
    int2*     edata2  = (int2*)(base + alloc((size_t)n * BSTRIDE * 8));
    unsigned short* xwh = (unsigned short*)(base + alloc((size_t)n * DIM * 2));

    // edge-slice assignment proportional to carriers' native durations
    struct Slice { int e0, e1, blocks; };
    int cur = 0;
    auto take = [&](int want, int bs) {
        Slice s; s.e0 = cur;
        int t = want; if (cur + t > ne) t = ne - cur;
        s.e1 = cur + t; cur = s.e1;
        s.blocks = (t + bs - 1) / bs;
        return s;
    };
    Slice sl_score = take(350000, 256);
    Slice sl_fb    = take(200000, 1024);
    Slice sl_col   = take(150000, 256);
    Slice sl_rank  = take(120000, 256);
    Slice sl_gru   = take(350000, 128);
    Slice sl_xw    = take(ne, 256);        // remainder (~430k)

    int scoreMB = (n * 16 + 255) / 256;
    int colMB   = (n + 255) / 256;
    int xwMB    = ((n + 63) / 64) * 2;

    hipMemsetAsync(base + zero_beg, 0, zero_len, stream);
    k_score_deg<<<scoreMB + sl_score.blocks, 256, 0, stream>>>(
        x, p, score, hist, n, sl_score.blocks, ei, ew, packed, edata2,
        sl_score.e0, sl_score.e1, ne);
    k_findbin_deg<<<1 + sl_fb.blocks, 1024, 0, stream>>>(
        hist, binfo, TOPK, p, pinv, ei, ew, packed, edata2, sl_fb.e0, sl_fb.e1, ne);
    k_collect_deg<<<colMB + sl_col.blocks, 256, 0, stream>>>(
        score, binfo, counter, cval, cidx, n, sl_col.blocks, ei, ew, packed, edata2,
        sl_col.e0, sl_col.e1, ne);
    k_rank_deg<<<(CAP / 256) + sl_rank.blocks, 256, 0, stream>>>(
        cval, cidx, counter, perm, vals, TOPK, sl_rank.blocks, ei, ew, packed, edata2,
        sl_rank.e0, sl_rank.e1, ne);
    k_gru_deg<<<DIM + sl_gru.blocks, 128, 0, stream>>>(
        x, perm, vals, pinv, W0, w_ih, w_hh, b_ih, b_hh, WhT, sl_gru.blocks, ei, ew,
        packed, edata2, sl_gru.e0, sl_gru.e1, ne);
    k_xw_deg<<<xwMB + sl_xw.blocks, 256, 0, stream>>>(
        x, WhT, xwh, n, sl_xw.blocks, ei, ew, packed, edata2, sl_xw.e0, sl_xw.e1, ne);
    k_dinv<<<(n + 255) / 256, 256, 0, stream>>>(packed, dinv, cnt, n);
    long long g_threads = (long long)n * 16;
    k_gather<<<(int)((g_threads + 255) / 256), 256, 0, stream>>>(
        xwh, dinv, cnt, edata2, w_lin, b_lin, out, n);
}

// Round 18
// 235.853 us; speedup vs baseline: 1.0336x; 1.0336x over previous
//
#include <hip/hip_runtime.h>
#include <hip/hip_bf16.h>
#include <math.h>

#define DIM 128
#define TOPK 128
#define CAP 4096
#define HSIZE 16384
#define HSHIFT 18          // f2k >> 18 -> 14-bit bin
#define HMUL 10937u        // odd -> bijective mod 2^14
#define BSTRIDE 64         // fixed slots per destination bucket (Poisson(16) tail << 64)

typedef __attribute__((ext_vector_type(8))) short bf16x8;
typedef __attribute__((ext_vector_type(4))) float f32x4;

__device__ __forceinline__ unsigned f2k(float f) {
    unsigned b = __float_as_uint(f);
    return (b & 0x80000000u) ? ~b : (b | 0x80000000u);
}

__device__ __forceinline__ unsigned hidx(unsigned bin) {
    return (bin * HMUL) & (HSIZE - 1u);
}

// round-to-nearest-even bf16 (as high 16 bits of fp32)
__device__ __forceinline__ unsigned bf16rn(float v) {
    unsigned u = __float_as_uint(v);
    u += 0x7fffu + ((u >> 16) & 1u);
    return u >> 16;
}

__device__ __forceinline__ unsigned pack2bf(float lo, float hi) {
    return (bf16rn(hi) << 16) | bf16rn(lo);
}

// one u64 atomic per edge: [63:40] count, [39:0] fixed-point weight sum (2^-32).
// seq from returned old value -> direct store of (src, raw w) into fixed bucket.
__device__ __forceinline__ void deg_edge(const int* __restrict__ ei, const float* __restrict__ ew,
                                         unsigned long long* __restrict__ packed,
                                         int2* __restrict__ edata2, int ne, int e) {
    int c = ei[ne + e];
    float w = ew[e];
    unsigned long long fx = (unsigned long long)((double)w * 4294967296.0);
    unsigned long long old = atomicAdd(&packed[c], (1ull << 40) | fx);
    int seq = (int)(old >> 40);
    if (seq < BSTRIDE)
        edata2[((size_t)c << 6) + seq] = make_int2(ei[e], __float_as_int(w));
}

// Bresenham interleave of degB deg-blocks among T total blocks.
__device__ __forceinline__ bool pick_deg(int bid, int degB, int T, int* mi, int* di) {
    long long a = (long long)bid * degB;
    int before = (int)(a / T);
    if ((int)((a + degB) / T) > before) { *di = before; return true; }
    *mi = bid - before;
    return false;
}

// 16 lanes per node (2x float4 each): UNSCALED score + spread-hist bin, + deg slice
__global__ void k_score_deg(const float* __restrict__ x, const float* __restrict__ p,
                            float* __restrict__ score,
                            unsigned* __restrict__ hist, int n,
                            int degB, const int* __restrict__ ei, const float* __restrict__ ew,
                            unsigned long long* __restrict__ packed,
                            int2* __restrict__ edata2,
                            int e0, int e1, int ne) {
    int mi, di;
    if (pick_deg((int)blockIdx.x, degB, (int)gridDim.x, &mi, &di)) {
        int e = e0 + di * 256 + (int)threadIdx.x;
        if (e < e1) deg_edge(ei, ew, packed, edata2, ne, e);
        return;
    }
    int gid = mi * 256 + (int)threadIdx.x;
    int node = gid >> 4, lane = gid & 15;
    if (node >= n) return;
    const float4* xr = (const float4*)(x) + (size_t)node * 32;
    const float4* p4 = (const float4*)p;
    float4 a0 = xr[lane * 2], a1 = xr[lane * 2 + 1];
    float4 b0 = p4[lane * 2], b1 = p4[lane * 2 + 1];
    float acc = a0.x * b0.x + a0.y * b0.y + a0.z * b0.z + a0.w * b0.w +
                a1.x * b1.x + a1.y * b1.y + a1.z * b1.z + a1.w * b1.w;
#pragma unroll
    for (int m = 8; m >= 1; m >>= 1) acc += __shfl_xor(acc, m, 16);
    if (lane == 0) {
        score[node] = acc;                     // raw dot; ordering is scale-invariant
        atomicAdd(&hist[hidx(f2k(acc) >> HSHIFT)], 1u);
    }
}

// block 0: find threshold bin (16 bins/thread) + compute pinv; other blocks: deg slice
__global__ void k_findbin_deg(const unsigned* __restrict__ hist, unsigned* __restrict__ binfo,
                              int k, const float* __restrict__ p, float* __restrict__ pinv,
                              const int* __restrict__ ei, const float* __restrict__ ew,
                              unsigned long long* __restrict__ packed,
                              int2* __restrict__ edata2,
                              int e0, int e1, int ne) {
    if (blockIdx.x > 0) {
        int e = e0 + ((int)blockIdx.x - 1) * 1024 + (int)threadIdx.x;
        if (e < e1) deg_edge(ei, ew, packed, edata2, ne, e);
        return;
    }
    __shared__ unsigned csum[1024];
    __shared__ float ps[DIM];
    int t = threadIdx.x;
    if (t < DIM) { float v = p[t]; ps[t] = v * v; }
    unsigned hv[16];
    unsigned s = 0;
#pragma unroll
    for (int j = 0; j < 16; ++j) {
        hv[j] = hist[hidx(t * 16 + j)];
        s += hv[j];
    }
    csum[t] = s;
    __syncthreads();
    if (t < 64) {
        for (int off = 64; off > 0; off >>= 1) {
            if (t < off) ps[t] += ps[t + off];
        }
    }
    if (t == 0) pinv[0] = 1.0f / sqrtf(ps[0] + ps[1]);   // tree leaves ps[0],ps[1] summed
    for (int off = 1; off < 1024; off <<= 1) {
        unsigned v = (t + off < 1024) ? csum[t + off] : 0u;
        __syncthreads();
        csum[t] += v;
        __syncthreads();
    }
    unsigned run = (t + 1 < 1024) ? csum[t + 1] : 0u;
#pragma unroll
    for (int j = 15; j >= 0; --j) {
        unsigned h = hv[j];
        if (h > 0u && run < (unsigned)k && run + h >= (unsigned)k) {
            binfo[0] = (unsigned)(t * 16 + j);
            binfo[1] = run;
        }
        run += h;
    }
}

__global__ void k_collect_deg(const float* __restrict__ score, const unsigned* __restrict__ binfo,
                              unsigned* __restrict__ counter, float* __restrict__ cval,
                              int* __restrict__ cidx, int n,
                              int degB, const int* __restrict__ ei, const float* __restrict__ ew,
                              unsigned long long* __restrict__ packed,
                              int2* __restrict__ edata2,
                              int e0, int e1, int ne) {
    int mi, di;
    if (pick_deg((int)blockIdx.x, degB, (int)gridDim.x, &mi, &di)) {
        int e = e0 + di * 256 + (int)threadIdx.x;
        if (e < e1) deg_edge(ei, ew, packed, edata2, ne, e);
        return;
    }
    int i = mi * 256 + (int)threadIdx.x;
    if (i >= n) return;
    float s = score[i];
    if ((f2k(s) >> HSHIFT) >= binfo[0]) {
        unsigned pos = atomicAdd(counter, 1u);
        if (pos < CAP) { cval[pos] = s; cidx[pos] = i; }
    }
}

// rank-based exact top-k (matches jax.lax.top_k: desc, lower index wins ties)
__global__ void k_rank_deg(const float* __restrict__ cval, const int* __restrict__ cidx,
                           const unsigned* __restrict__ counter, int* __restrict__ perm,
                           float* __restrict__ vals, int k,
                           int degB, const int* __restrict__ ei, const float* __restrict__ ew,
                           unsigned long long* __restrict__ packed,
                           int2* __restrict__ edata2,
                           int e0, int e1, int ne) {
    int mi, di;
    if (pick_deg((int)blockIdx.x, degB, (int)gridDim.x, &mi, &di)) {
        int e = e0 + di * 256 + (int)threadIdx.x;
        if (e < e1) deg_edge(ei, ew, packed, edata2, ne, e);
        return;
    }
    int i = mi * 256 + (int)threadIdx.x;
    unsigned cnt = counter[0];
    int m = (cnt < (unsigned)CAP) ? (int)cnt : CAP;
    if (i >= m) return;
    float v = cval[i]; int id = cidx[i];
    int rank = 0;
    for (int j = 0; j < m; ++j) {
        float vj = cval[j]; int ij = cidx[j];
        if (vj > v || (vj == v && ij < id)) ++rank;
    }
    if (rank < k) { perm[rank] = id; vals[rank] = v; }
}

// GRU with fused x_tilde (vals scaled by pinv here) + deg slice; writes W^T bf16
__global__ void k_gru_deg(const float* __restrict__ x, const int* __restrict__ perm,
                          const float* __restrict__ vals, const float* __restrict__ pinv,
                          const float* __restrict__ W0,
                          const float* __restrict__ w_ih, const float* __restrict__ w_hh,
                          const float* __restrict__ b_ih, const float* __restrict__ b_hh,
                          unsigned short* __restrict__ WhT,
                          int degB, const int* __restrict__ ei, const float* __restrict__ ew,
                          unsigned long long* __restrict__ packed,
                          int2* __restrict__ edata2,
                          int e0, int e1, int ne) {
    __shared__ float sx[DIM], sh[DIM];
    int mi, di;
    if (pick_deg((int)blockIdx.x, degB, (int)gridDim.x, &mi, &di)) {
        int e = e0 + di * 128 + (int)threadIdx.x;
        if (e < e1) deg_edge(ei, ew, packed, edata2, ne, e);
        return;
    }
    int i = mi, c = threadIdx.x;
    sx[c] = x[(size_t)perm[i] * DIM + c] * tanhf(vals[i] * pinv[0]);
    sh[c] = W0[i * DIM + c];
    __syncthreads();
    float gr = b_ih[c], gz = b_ih[DIM + c], gn = b_ih[2 * DIM + c];
    float hr = b_hh[c], hz = b_hh[DIM + c], hn = b_hh[2 * DIM + c];
    const float* wr = w_ih + (size_t)c * DIM;
    const float* wz = w_ih + (size_t)(DIM + c) * DIM;
    const float* wn = w_ih + (size_t)(2 * DIM + c) * DIM;
    const float* ur = w_hh + (size_t)c * DIM;
    const float* uz = w_hh + (size_t)(DIM + c) * DIM;
    const float* un = w_hh + (size_t)(2 * DIM + c) * DIM;
    for (int d = 0; d < DIM; ++d) {
        float xd = sx[d], hd = sh[d];
        gr += xd * wr[d]; gz += xd * wz[d]; gn += xd * wn[d];
        hr += hd * ur[d]; hz += hd * uz[d]; hn += hd * un[d];
    }
    float r = 1.0f / (1.0f + expf(-(gr + hr)));
    float z = 1.0f / (1.0f + expf(-(gz + hz)));
    float nn = tanhf(gn + r * hn);
    float wv = (1.0f - z) * nn + z * sh[c];
    WhT[(size_t)c * DIM + i] = (unsigned short)bf16rn(wv);   // transposed bf16
}

// unpack packed -> dinv + cnt (runs after ALL deg atomics are done)
__global__ void k_dinv(const unsigned long long* __restrict__ packed,
                       float* __restrict__ dinv, int* __restrict__ cnt, int n) {
    int i = blockIdx.x * blockDim.x + threadIdx.x;
    if (i < n) {
        unsigned long long pk = packed[i];
        float sumw = (float)((double)(pk & ((1ull << 40) - 1ull)) * (1.0 / 4294967296.0));
        dinv[i] = rsqrtf(1.0f + sumw);
        cnt[i] = (int)(pk >> 40);
    }
}

// xw = x @ W, rows pre-scaled by dinv[row] -> bf16 (xwd). MFMA 16x16x32, 64x64 tile,
// 4 waves, 16KB LDS (bf16 x-tile, granule-XOR swizzle). W^T bf16 from global (L2).
__global__ __launch_bounds__(256) void k_xw(const float* __restrict__ x,
                                            const unsigned short* __restrict__ WhT,
                                            const float* __restrict__ dinv,
                                            unsigned short* __restrict__ xwh, int n) {
    __shared__ unsigned short xs[64 * DIM];   // 16KB: [r][k] bf16, granule g^=(r&7)
    int nTr = (n + 63) / 64;
    int mi = (int)blockIdx.x;
    int r0 = (mi % nTr) * 64;
    int c0 = (mi / nTr) * 64;
    int t = threadIdx.x;
    {
        int r = t >> 2;
        int row = r0 + r; if (row >= n) row = n - 1;
        const float4* xr = (const float4*)(x + (size_t)row * DIM);
#pragma unroll
        for (int j = 0; j < 4; ++j) {
            int g = (t & 3) + 4 * j;
            float4 lo = xr[g * 2];
            float4 hi = xr[g * 2 + 1];
            uint4 o;
            o.x = pack2bf(lo.x, lo.y);
            o.y = pack2bf(lo.z, lo.w);
            o.z = pack2bf(hi.x, hi.y);
            o.w = pack2bf(hi.z, hi.w);
            *(uint4*)&xs[r * DIM + ((g ^ (r & 7)) << 3)] = o;
        }
    }
    __syncthreads();
    int wid = t >> 6, lane = t & 63;
    int lr = wid * 16 + (lane & 15);
    int kg = lane >> 4;
    int cA = lane & 15;
    f32x4 acc[4] = {{0.f,0.f,0.f,0.f},{0.f,0.f,0.f,0.f},{0.f,0.f,0.f,0.f},{0.f,0.f,0.f,0.f}};
    const bf16x8* wt = (const bf16x8*)WhT;
#pragma unroll
    for (int q = 0; q < 4; ++q) {
        bf16x8 a = *(const bf16x8*)&xs[lr * DIM + (((q * 4 + kg) ^ (lr & 7)) << 3)];
#pragma unroll
        for (int ct = 0; ct < 4; ++ct) {
            bf16x8 b = wt[(size_t)(c0 + ct * 16 + cA) * 16 + q * 4 + kg];
            acc[ct] = __builtin_amdgcn_mfma_f32_16x16x32_bf16(a, b, acc[ct], 0, 0, 0);
        }
    }
    int orow = r0 + wid * 16 + (lane >> 4) * 4;
#pragma unroll
    for (int reg = 0; reg < 4; ++reg) {
        int row = orow + reg;
        if (row < n) {
            float dr = dinv[row];
            unsigned short* dst = xwh + (size_t)row * DIM + c0 + cA;
#pragma unroll
            for (int ct = 0; ct < 4; ++ct)
                dst[ct * 16] = (unsigned short)bf16rn(acc[ct][reg] * dr);
        }
    }
}

// per-node gather + fused relu-linear head: 16 lanes per node, 8 bf16 (16B) each.
// xwd rows are pre-scaled by dinv[src]; per-edge weight is raw w (shfl only).
// out[c] = dinv[c] * (relu(acc) . w_lin) + b  (relu commutes with positive scale)
__global__ __launch_bounds__(256) void k_gather(const unsigned short* __restrict__ xwh,
        const float* __restrict__ dinv, const int* __restrict__ cnt,
        const int2* __restrict__ edata2, const float* __restrict__ w_lin,
        const float* __restrict__ b_lin, float* __restrict__ out, int n) {
    int gid = blockIdx.x * 256 + threadIdx.x;
    int c = gid >> 4, lane = gid & 15;
    if (c >= n) return;
    const uint4* xw4 = (const uint4*)xwh;
    float acc[8];
    {
        uint4 a = xw4[(size_t)c * 16 + lane];   // xwd[c] = dinv[c]*xw[c]
        unsigned w[4] = {a.x, a.y, a.z, a.w};
#pragma unroll
        for (int q = 0; q < 4; ++q) {
            acc[2 * q]     = __uint_as_float(w[q] << 16);
            acc[2 * q + 1] = __uint_as_float(w[q] & 0xffff0000u);
        }
    }
    int m0 = cnt[c]; if (m0 > BSTRIDE) m0 = BSTRIDE;
    const int2* bkt = edata2 + ((size_t)c << 6);
    for (int base = 0; base < m0; base += 16) {
        int m = m0 - base; if (m > 16) m = 16;
        int2 ed = (base + lane < m0) ? bkt[base + lane] : make_int2(0, 0);
        for (int j0 = 0; j0 < m; j0 += 8) {
            uint4 v[8]; float nr[8];
#pragma unroll
            for (int jj = 0; jj < 8; ++jj) {
                int j = j0 + jj;
                int src = __shfl(ed.x, j & 15, 16);
                float w = __int_as_float(__shfl(ed.y, j & 15, 16));
                nr[jj] = (j < m) ? w : 0.0f;
                v[jj] = xw4[(size_t)src * 16 + lane];
            }
#pragma unroll
            for (int jj = 0; jj < 8; ++jj) {
                unsigned w[4] = {v[jj].x, v[jj].y, v[jj].z, v[jj].w};
#pragma unroll
                for (int q = 0; q < 4; ++q) {
                    acc[2 * q]     += __uint_as_float(w[q] << 16) * nr[jj];
                    acc[2 * q + 1] += __uint_as_float(w[q] & 0xffff0000u) * nr[jj];
                }
            }
        }
    }
    float4 wla = ((const float4*)w_lin)[lane * 2];
    float4 wlb = ((const float4*)w_lin)[lane * 2 + 1];
    float r = fmaxf(acc[0], 0.0f) * wla.x + fmaxf(acc[1], 0.0f) * wla.y +
              fmaxf(acc[2], 0.0f) * wla.z + fmaxf(acc[3], 0.0f) * wla.w +
              fmaxf(acc[4], 0.0f) * wlb.x + fmaxf(acc[5], 0.0f) * wlb.y +
              fmaxf(acc[6], 0.0f) * wlb.z + fmaxf(acc[7], 0.0f) * wlb.w;
#pragma unroll
    for (int m = 8; m >= 1; m >>= 1) r += __shfl_xor(r, m, 16);
    if (lane == 0) out[c] = dinv[c] * r + b_lin[0];
}

extern "C" void kernel_launch(void* const* d_in, const int* in_sizes, int n_in,
                              void* d_out, int out_size, void* d_ws, size_t ws_size,
                              hipStream_t stream) {
    const float* x     = (const float*)d_in[0];
    const int*   ei    = (const int*)d_in[1];
    const float* ew    = (const float*)d_in[2];
    const float* p     = (const float*)d_in[3];
    const float* W0    = (const float*)d_in[4];
    const float* w_ih  = (const float*)d_in[5];
    const float* w_hh  = (const float*)d_in[6];
    const float* b_ih  = (const float*)d_in[7];
    const float* b_hh  = (const float*)d_in[8];
    const float* w_lin = (const float*)d_in[9];
    const float* b_lin = (const float*)d_in[10];
    float* out = (float*)d_out;
    int n  = in_sizes[0] / DIM;
    int ne = in_sizes[2];
    (void)n_in; (void)out_size; (void)ws_size;

    char* base = (char*)d_ws;
    size_t o = 0;
    auto alloc = [&](size_t b) { size_t r = o; o += (b + 255) & ~(size_t)255; return r; };
    // packed+hist+counter contiguous -> single async memset zeroes all three
    size_t zero_beg = o;
    unsigned long long* packed = (unsigned long long*)(base + alloc((size_t)n * 8));
    unsigned* hist    = (unsigned*)(base + alloc(HSIZE * 4));
    unsigned* counter = (unsigned*)(base + alloc(256));
    size_t zero_len = o - zero_beg;
    float*    score   = (float*)(base + alloc((size_t)n * 4));
    unsigned* binfo   = (unsigned*)(base + alloc(256));
    float*    cval    = (float*)(base + alloc((size_t)CAP * 4));
    int*      cidx    = (int*)(base + alloc((size_t)CAP * 4));
    int*      perm    = (int*)(base + alloc(TOPK * 4));
    float*    vals    = (float*)(base + alloc(TOPK * 4));
    float*    pinv    = (float*)(base + alloc(256));
    unsigned short* WhT = (unsigned short*)(base + alloc(DIM * DIM * 2));
    float*    dinv    = (float*)(base + alloc((size_t)n * 4));
    int*      cnt     = (int*)(base + alloc((size_t)n * 4));
    int2*     edata2  = (int2*)(base + alloc((size_t)n * BSTRIDE * 8));
    unsigned short* xwh = (unsigned short*)(base + alloc((size_t)n * DIM * 2));

    // ALL deg atomics absorbed by the 5 pre-xw carriers
    struct Slice { int e0, e1, blocks; };
    int cur = 0;
    auto take = [&](int want, int bs) {
        Slice s; s.e0 = cur;
        int t = want; if (cur + t > ne) t = ne - cur;
        s.e1 = cur + t; cur = s.e1;
        s.blocks = (t + bs - 1) / bs;
        return s;
    };
    Slice sl_score = take((int)((long long)ne * 28 / 100), 256);
    Slice sl_fb    = take((int)((long long)ne * 19 / 100), 1024);
    Slice sl_col   = take((int)((long long)ne * 16 / 100), 256);
    Slice sl_rank  = take((int)((long long)ne * 12 / 100), 256);
    Slice sl_gru   = take(ne, 128);        // remainder (~25%)

    int scoreMB = (n * 16 + 255) / 256;
    int colMB   = (n + 255) / 256;
    int xwB     = ((n + 63) / 64) * 2;

    hipMemsetAsync(base + zero_beg, 0, zero_len, stream);
    k_score_deg<<<scoreMB + sl_score.blocks, 256, 0, stream>>>(
        x, p, score, hist, n, sl_score.blocks, ei, ew, packed, edata2,
        sl_score.e0, sl_score.e1, ne);
    k_findbin_deg<<<1 + sl_fb.blocks, 1024, 0, stream>>>(
        hist, binfo, TOPK, p, pinv, ei, ew, packed, edata2, sl_fb.e0, sl_fb.e1, ne);
    k_collect_deg<<<colMB + sl_col.blocks, 256, 0, stream>>>(
        score, binfo, counter, cval, cidx, n, sl_col.blocks, ei, ew, packed, edata2,
        sl_col.e0, sl_col.e1, ne);
    k_rank_deg<<<(CAP / 256) + sl_rank.blocks, 256, 0, stream>>>(
        cval, cidx, counter, perm, vals, TOPK, sl_rank.blocks, ei, ew, packed, edata2,
        sl_rank.e0, sl_rank.e1, ne);
    k_gru_deg<<<DIM + sl_gru.blocks, 128, 0, stream>>>(
        x, perm, vals, pinv, W0, w_ih, w_hh, b_ih, b_hh, WhT, sl_gru.blocks, ei, ew,
        packed, edata2, sl_gru.e0, sl_gru.e1, ne);
    k_dinv<<<(n + 255) / 256, 256, 0, stream>>>(packed, dinv, cnt, n);
    k_xw<<<xwB, 256, 0, stream>>>(x, WhT, dinv, xwh, n);
    long long g_threads = (long long)n * 16;
    k_gather<<<(int)((g_threads + 255) / 256), 256, 0, stream>>>(
        xwh, dinv, cnt, edata2, w_lin, b_lin, out, n);
}